// Round 4
// baseline (1514.202 us; speedup 1.0000x reference)
//
#include <hip/hip_runtime.h>
#include <hip/hip_bf16.h>
#include <math.h>

// ---------------- problem constants ----------------
constexpr int GN_N  = 100000;   // nodes
constexpr int GN_E  = 1000000;  // edges
constexpr int GN_F  = 500;      // input features
constexpr int GN_H  = 64;       // hidden
constexpr int GN_2H = 128;      // mlp hidden
constexpr int GN_C  = 3;        // classes
constexpr float GN_EPS_MSG = 1e-7f;
constexpr float GN_LN_EPS  = 1e-5f;

// ---------------- prep: zero cursor + edge-dtype detect (parallel) ----------
// Reference declares int64 edge_index, but JAX without x64 delivers int32. An
// int64 view of random int32 index pairs has hi-word = another random index
// (nonzero w.h.p.), so 256 parallel 0<=v<N range checks <=> real int64.
__global__ void k_prep(int* __restrict__ cursor, const long long* __restrict__ e64,
                       int* __restrict__ flag) {
    int i = blockIdx.x * blockDim.x + threadIdx.x;
    if (i < GN_N) cursor[i] = 0;
    if (blockIdx.x == 0) {
        __shared__ int ok;
        if (threadIdx.x == 0) ok = 1;
        __syncthreads();
        long long v = e64[threadIdx.x];          // 256 parallel loads, 1 round trip
        if (v < 0 || v >= (long long)GN_N) ok = 0; // benign race: all write 0
        __syncthreads();
        if (threadIdx.x == 0) *flag = ok;
    }
}

// ---------------- CSR build ----------------
__global__ void k_hist(const void* eidx, const int* __restrict__ flag,
                       int* __restrict__ deg) {
    int e = blockIdx.x * blockDim.x + threadIdx.x;
    if (e >= GN_E) return;
    int d;
    if (*flag) d = (int)((const long long*)eidx)[GN_E + e];
    else       d = ((const int*)eidx)[GN_E + e];
    atomicAdd(&deg[d], 1);
}

__global__ void k_scan1(const int* __restrict__ deg, int* __restrict__ rowptr,
                        int* __restrict__ blksums) {
    __shared__ int sh[1024];
    int tid = threadIdx.x;
    int i = blockIdx.x * 1024 + tid;
    int v = (i < GN_N) ? deg[i] : 0;
    sh[tid] = v;
    __syncthreads();
    for (int o = 1; o < 1024; o <<= 1) {
        int add = (tid >= o) ? sh[tid - o] : 0;
        __syncthreads();
        sh[tid] += add;
        __syncthreads();
    }
    if (i < GN_N) rowptr[i + 1] = sh[tid];
    if (tid == 1023) blksums[blockIdx.x] = sh[1023];
}

// one-block parallel exclusive scan of the <=128 block sums
__global__ void k_scan2(int* __restrict__ blksums, int nblk) {
    __shared__ int sh[128];
    int tid = threadIdx.x;               // 128 threads
    int v = (tid < nblk) ? blksums[tid] : 0;
    sh[tid] = v;
    __syncthreads();
    for (int o = 1; o < 128; o <<= 1) {
        int add = (tid >= o) ? sh[tid - o] : 0;
        __syncthreads();
        sh[tid] += add;
        __syncthreads();
    }
    if (tid < nblk) blksums[tid] = sh[tid] - v;   // exclusive
}

// finalizes rowptr AND initializes the scatter cursor (fused)
__global__ void k_scan3(int* __restrict__ rowptr, int* __restrict__ cursor,
                        const int* __restrict__ blksums) {
    int i = blockIdx.x * 1024 + threadIdx.x;
    if (i < GN_N) {
        int v = rowptr[i + 1] + blksums[blockIdx.x];
        rowptr[i + 1] = v;
        cursor[i + 1] = v;   // cursor has +8 pad; [N] write is safe
    }
    if (i == 0) { rowptr[0] = 0; cursor[0] = 0; }
}

__global__ void k_scatter(const void* eidx, const int* __restrict__ flag,
                          int* __restrict__ cursor, int* __restrict__ csr_src) {
    int e = blockIdx.x * blockDim.x + threadIdx.x;
    if (e >= GN_E) return;
    int s, d;
    if (*flag) { const long long* p = (const long long*)eidx; s = (int)p[e]; d = (int)p[GN_E + e]; }
    else       { const int*       p = (const int*)eidx;       s = p[e];      d = p[GN_E + e]; }
    int pos = atomicAdd(&cursor[d], 1);
    csr_src[pos] = s;
}

// ---------------- encoder: h = x @ enc_W + enc_b ----------------
// 4 waves/block, 8 rows/wave (32 rows/block), lane = output col.
// W staged in LDS in 100-row k-tiles (25.6 KB): W global traffic = 1 read per
// BLOCK (3125 x 128 KB = 400 MB L2) instead of 1 per wave. x loads are
// wave-uniform float4 broadcasts (one cacheline round-trip each), each row
// read exactly once. fp32 VALU floor for this GEMM: ~41 us.
constexpr int ENC_KT = 100;
__global__ __launch_bounds__(256) void k_enc(const float* __restrict__ x,
        const float* __restrict__ W, const float* __restrict__ b,
        float* __restrict__ out) {
    __shared__ float ws[ENC_KT * GN_H];          // 25.6 KB
    int tid  = threadIdx.x;
    int lane = tid & 63;
    int wid  = tid >> 6;
    int row0 = blockIdx.x * 32 + wid * 8;        // 3125*32 == 100000 exactly
    float acc0 = 0.f, acc1 = 0.f, acc2 = 0.f, acc3 = 0.f;
    float acc4 = 0.f, acc5 = 0.f, acc6 = 0.f, acc7 = 0.f;
    for (int kt = 0; kt < GN_F; kt += ENC_KT) {
        __syncthreads();                          // protect previous tile
        for (int i = tid * 4; i < ENC_KT * GN_H; i += 256 * 4)
            *(float4*)&ws[i] = *(const float4*)&W[kt * GN_H + i];
        __syncthreads();
        for (int k = 0; k < ENC_KT; k += 4) {
            float w0 = ws[(k + 0) * GN_H + lane];
            float w1 = ws[(k + 1) * GN_H + lane];
            float w2 = ws[(k + 2) * GN_H + lane];
            float w3 = ws[(k + 3) * GN_H + lane];
            #define ENC_ROW(r, accv)                                          \
            {   float4 xv = *(const float4*)&x[(size_t)(row0 + r) * GN_F + kt + k]; \
                accv += xv.x * w0 + xv.y * w1 + xv.z * w2 + xv.w * w3; }
            ENC_ROW(0, acc0) ENC_ROW(1, acc1) ENC_ROW(2, acc2) ENC_ROW(3, acc3)
            ENC_ROW(4, acc4) ENC_ROW(5, acc5) ENC_ROW(6, acc6) ENC_ROW(7, acc7)
            #undef ENC_ROW
        }
    }
    float bias = b[lane];
    out[(size_t)(row0 + 0) * GN_H + lane] = acc0 + bias;
    out[(size_t)(row0 + 1) * GN_H + lane] = acc1 + bias;
    out[(size_t)(row0 + 2) * GN_H + lane] = acc2 + bias;
    out[(size_t)(row0 + 3) * GN_H + lane] = acc3 + bias;
    out[(size_t)(row0 + 4) * GN_H + lane] = acc4 + bias;
    out[(size_t)(row0 + 5) * GN_H + lane] = acc5 + bias;
    out[(size_t)(row0 + 6) * GN_H + lane] = acc6 + bias;
    out[(size_t)(row0 + 7) * GN_H + lane] = acc7 + bias;
}

// ---------------- GENConv softmax aggregation (online, single pass) ----------
// One wave per dst node, lane = channel. Online softmax (re-association of the
// reference's max-then-sum; agg = num/den == sum(m * a/denom), denom uniform
// per dst). Edge loop unrolled x2 so two h[src] gathers are in flight per
// dependent-VALU update step.
__global__ __launch_bounds__(256) void k_conv_agg(const float* __restrict__ h,
        const int* __restrict__ rowptr, const int* __restrict__ csr_src,
        const float* __restrict__ t_all, int layer, float* __restrict__ out) {
    int lane = threadIdx.x & 63;
    int node = blockIdx.x * 4 + (threadIdx.x >> 6);
    if (node >= GN_N) return;
    float t = t_all[layer];
    int beg = rowptr[node], end = rowptr[node + 1];
    float mx = -INFINITY, den = 0.f, num = 0.f;
    int e = beg;
    for (; e + 1 < end; e += 2) {
        int s0 = csr_src[e];
        int s1 = csr_src[e + 1];
        float v0 = h[(size_t)s0 * GN_H + lane];   // independent gathers,
        float v1 = h[(size_t)s1 * GN_H + lane];   // both in flight
        float m0 = fmaxf(v0, 0.f) + GN_EPS_MSG;
        float z0 = m0 * t;
        float nm0 = fmaxf(mx, z0);
        float sc0 = __expf(mx - nm0);
        float a0  = __expf(z0 - nm0);
        den = den * sc0 + a0;
        num = num * sc0 + m0 * a0;
        mx = nm0;
        float m1 = fmaxf(v1, 0.f) + GN_EPS_MSG;
        float z1 = m1 * t;
        float nm1 = fmaxf(mx, z1);
        float sc1 = __expf(mx - nm1);
        float a1  = __expf(z1 - nm1);
        den = den * sc1 + a1;
        num = num * sc1 + m1 * a1;
        mx = nm1;
    }
    if (e < end) {
        int s = csr_src[e];
        float v = h[(size_t)s * GN_H + lane];
        float m = fmaxf(v, 0.f) + GN_EPS_MSG;
        float z = m * t;
        float nm = fmaxf(mx, z);
        float sc = __expf(mx - nm);
        float a  = __expf(z - nm);
        den = den * sc + a;
        num = num * sc + m * a;
        mx = nm;
    }
    float agg = (end > beg) ? (num / den) : 0.f;
    out[(size_t)node * GN_H + lane] = agg + h[(size_t)node * GN_H + lane];
}

// ---------------- GENConv MLP (+ DeepGCN post-block / + fused final head) ----
// One wave per FOUR nodes. W1/W2 in 64 KB LDS + 12 KB wave-private staging
// (76 KB -> 2 blocks/CU). Operand broadcast via uniform-address LDS reads.
// mode 0: buf[n] = mlp(buf[n])
// mode 1: buf[n] = h_old[n] + relu(LN(mlp(buf[n]), ng, nb))
// mode 2: mode 1, then out[n] = relu(LN(r, ng0, nb0)) @ linW + linb
//         (no buf write -- saves a 25.6MB store + the separate final kernel)
__global__ __launch_bounds__(256) void k_conv_mlp(float* buf,
        const float* __restrict__ h_old,
        const float* __restrict__ W1, const float* __restrict__ b1,
        const float* __restrict__ g1, const float* __restrict__ be1,
        const float* __restrict__ W2, const float* __restrict__ b2,
        const float* __restrict__ ng, const float* __restrict__ nb,
        const float* __restrict__ ng0, const float* __restrict__ nb0,
        const float* __restrict__ linW, const float* __restrict__ linb,
        float* __restrict__ out, int mode) {
    __shared__ float w1s[GN_H * GN_2H];     // 32 KB, [k][j] j=0..127
    __shared__ float w2s[GN_2H * GN_H];     // 32 KB, [j][c] c=0..63
    __shared__ float xbuf[4][4][GN_H];      //  4 KB, [wave][node][k]
    __shared__ float hbuf[4][4][GN_2H];     //  8 KB, [wave][node][j]
    int tid = threadIdx.x;
    for (int i = tid * 4; i < GN_H * GN_2H; i += 256 * 4) {
        *(float4*)&w1s[i] = *(const float4*)&W1[i];
        *(float4*)&w2s[i] = *(const float4*)&W2[i];
    }
    __syncthreads();
    int lane = tid & 63;
    int wid  = tid >> 6;
    float b1a = b1[2 * lane], b1b = b1[2 * lane + 1];
    float g1a = g1[2 * lane], g1b = g1[2 * lane + 1];
    float e1a = be1[2 * lane], e1b = be1[2 * lane + 1];
    float b2c = b2[lane];
    float ngc = ng[lane], nbc = nb[lane];
    float ng0c = ng0[lane], nb0c = nb0[lane];
    float lw0 = linW[lane * GN_C + 0];
    float lw1 = linW[lane * GN_C + 1];
    float lw2 = linW[lane * GN_C + 2];

    for (int n0 = blockIdx.x * 16 + wid * 4; n0 < GN_N; n0 += gridDim.x * 16) {
        // stage the 4 input vectors (lane k of node n) into wave-private LDS
        xbuf[wid][0][lane] = buf[(size_t)(n0 + 0) * GN_H + lane];
        xbuf[wid][1][lane] = buf[(size_t)(n0 + 1) * GN_H + lane];
        xbuf[wid][2][lane] = buf[(size_t)(n0 + 2) * GN_H + lane];
        xbuf[wid][3][lane] = buf[(size_t)(n0 + 3) * GN_H + lane];
        // ---- y1[j] = dot(in, W1[:,j]) + b1[j]; lane holds j=2*lane, 2*lane+1
        float a00 = b1a, a01 = b1b, a10 = b1a, a11 = b1b;
        float a20 = b1a, a21 = b1b, a30 = b1a, a31 = b1b;
        #pragma unroll
        for (int k = 0; k < GN_H; k += 4) {
            float4 x0 = *(const float4*)&xbuf[wid][0][k];   // uniform-addr
            float4 x1 = *(const float4*)&xbuf[wid][1][k];   // broadcast reads
            float4 x2 = *(const float4*)&xbuf[wid][2][k];
            float4 x3 = *(const float4*)&xbuf[wid][3][k];
            #pragma unroll
            for (int kk = 0; kk < 4; ++kk) {
                float2 w = *(const float2*)&w1s[(k + kk) * GN_2H + 2 * lane];
                float e0 = (&x0.x)[kk], e1 = (&x1.x)[kk];
                float e2 = (&x2.x)[kk], e3 = (&x3.x)[kk];
                a00 += e0 * w.x; a01 += e0 * w.y;
                a10 += e1 * w.x; a11 += e1 * w.y;
                a20 += e2 * w.x; a21 += e2 * w.y;
                a30 += e3 * w.x; a31 += e3 * w.y;
            }
        }
        // ---- LayerNorm over 128 + relu, per node
        float s0 = a00 + a01, q0 = a00 * a00 + a01 * a01;
        float s1 = a10 + a11, q1 = a10 * a10 + a11 * a11;
        float s2 = a20 + a21, q2 = a20 * a20 + a21 * a21;
        float s3 = a30 + a31, q3 = a30 * a30 + a31 * a31;
        #pragma unroll
        for (int o = 1; o < 64; o <<= 1) {
            s0 += __shfl_xor(s0, o); q0 += __shfl_xor(q0, o);
            s1 += __shfl_xor(s1, o); q1 += __shfl_xor(q1, o);
            s2 += __shfl_xor(s2, o); q2 += __shfl_xor(q2, o);
            s3 += __shfl_xor(s3, o); q3 += __shfl_xor(q3, o);
        }
        #define LN128(sv, qv, aA, aB, hA, hB)                                  \
        float hA, hB;                                                          \
        {   float mu = sv * (1.f / 128.f);                                     \
            float var = qv * (1.f / 128.f) - mu * mu;                          \
            float rstd = rsqrtf(var + GN_LN_EPS);                              \
            hA = fmaxf((aA - mu) * rstd * g1a + e1a, 0.f);                     \
            hB = fmaxf((aB - mu) * rstd * g1b + e1b, 0.f); }
        LN128(s0, q0, a00, a01, h00, h01)
        LN128(s1, q1, a10, a11, h10, h11)
        LN128(s2, q2, a20, a21, h20, h21)
        LN128(s3, q3, a30, a31, h30, h31)
        #undef LN128
        // stage h1 (lane holds j=2l,2l+1 -> contiguous b64 write per node)
        *(float2*)&hbuf[wid][0][2 * lane] = make_float2(h00, h01);
        *(float2*)&hbuf[wid][1][2 * lane] = make_float2(h10, h11);
        *(float2*)&hbuf[wid][2][2 * lane] = make_float2(h20, h21);
        *(float2*)&hbuf[wid][3][2 * lane] = make_float2(h30, h31);
        // ---- y2[c] = dot(h1, W2[:,c]) + b2[c]; lane = c
        float c0 = b2c, c1 = b2c, c2 = b2c, c3 = b2c;
        #pragma unroll
        for (int j = 0; j < GN_2H; j += 4) {
            float w0 = w2s[(j + 0) * GN_H + lane];
            float w1 = w2s[(j + 1) * GN_H + lane];
            float w2 = w2s[(j + 2) * GN_H + lane];
            float w3 = w2s[(j + 3) * GN_H + lane];
            float4 hv0 = *(const float4*)&hbuf[wid][0][j];  // uniform-addr
            float4 hv1 = *(const float4*)&hbuf[wid][1][j];  // broadcast reads
            float4 hv2 = *(const float4*)&hbuf[wid][2][j];
            float4 hv3 = *(const float4*)&hbuf[wid][3][j];
            c0 += hv0.x * w0 + hv0.y * w1 + hv0.z * w2 + hv0.w * w3;
            c1 += hv1.x * w0 + hv1.y * w1 + hv1.z * w2 + hv1.w * w3;
            c2 += hv2.x * w0 + hv2.y * w1 + hv2.z * w2 + hv2.w * w3;
            c3 += hv3.x * w0 + hv3.y * w1 + hv3.z * w2 + hv3.w * w3;
        }
        if (mode == 0) {
            buf[(size_t)(n0 + 0) * GN_H + lane] = c0;
            buf[(size_t)(n0 + 1) * GN_H + lane] = c1;
            buf[(size_t)(n0 + 2) * GN_H + lane] = c2;
            buf[(size_t)(n0 + 3) * GN_H + lane] = c3;
            continue;
        }
        // ---- DeepGCN post-block: r = h_old + relu(LN64(c, ng, nb))
        float t0 = c0, u0 = c0 * c0, t1 = c1, u1 = c1 * c1;
        float t2 = c2, u2 = c2 * c2, t3 = c3, u3 = c3 * c3;
        #pragma unroll
        for (int o = 1; o < 64; o <<= 1) {
            t0 += __shfl_xor(t0, o); u0 += __shfl_xor(u0, o);
            t1 += __shfl_xor(t1, o); u1 += __shfl_xor(u1, o);
            t2 += __shfl_xor(t2, o); u2 += __shfl_xor(u2, o);
            t3 += __shfl_xor(t3, o); u3 += __shfl_xor(u3, o);
        }
        float r0, r1, r2, r3;
        #define LN64(tv, uv, cv, rv, idx)                                      \
        {   float mu = tv * (1.f / 64.f);                                      \
            float var = uv * (1.f / 64.f) - mu * mu;                           \
            float rstd = rsqrtf(var + GN_LN_EPS);                              \
            float cvn = fmaxf((cv - mu) * rstd * ngc + nbc, 0.f);              \
            rv = h_old[(size_t)(n0 + idx) * GN_H + lane] + cvn; }
        LN64(t0, u0, c0, r0, 0)
        LN64(t1, u1, c1, r1, 1)
        LN64(t2, u2, c2, r2, 2)
        LN64(t3, u3, c3, r3, 3)
        #undef LN64
        if (mode == 1) {
            buf[(size_t)(n0 + 0) * GN_H + lane] = r0;
            buf[(size_t)(n0 + 1) * GN_H + lane] = r1;
            buf[(size_t)(n0 + 2) * GN_H + lane] = r2;
            buf[(size_t)(n0 + 3) * GN_H + lane] = r3;
            continue;
        }
        // ---- mode 2: fused final head, out[n] = relu(LN64(r, ng0, nb0)) @ linW + linb
        float f0 = r0, v0 = r0 * r0, f1 = r1, v1 = r1 * r1;
        float f2 = r2, v2 = r2 * r2, f3 = r3, v3 = r3 * r3;
        #pragma unroll
        for (int o = 1; o < 64; o <<= 1) {
            f0 += __shfl_xor(f0, o); v0 += __shfl_xor(v0, o);
            f1 += __shfl_xor(f1, o); v1 += __shfl_xor(v1, o);
            f2 += __shfl_xor(f2, o); v2 += __shfl_xor(v2, o);
            f3 += __shfl_xor(f3, o); v3 += __shfl_xor(v3, o);
        }
        #define FINHEAD(fv, vv, rv, idx)                                       \
        {   float mu = fv * (1.f / 64.f);                                      \
            float var = vv * (1.f / 64.f) - mu * mu;                           \
            float rstd = rsqrtf(var + GN_LN_EPS);                              \
            float hn = fmaxf((rv - mu) * rstd * ng0c + nb0c, 0.f);             \
            float p0 = hn * lw0, p1 = hn * lw1, p2 = hn * lw2;                 \
            _Pragma("unroll")                                                  \
            for (int o = 1; o < 64; o <<= 1) {                                 \
                p0 += __shfl_xor(p0, o);                                       \
                p1 += __shfl_xor(p1, o);                                       \
                p2 += __shfl_xor(p2, o);                                       \
            }                                                                  \
            if (lane == 0) {                                                   \
                out[(size_t)(n0 + idx) * GN_C + 0] = p0 + linb[0];             \
                out[(size_t)(n0 + idx) * GN_C + 1] = p1 + linb[1];             \
                out[(size_t)(n0 + idx) * GN_C + 2] = p2 + linb[2];             \
            } }
        FINHEAD(f0, v0, r0, 0)
        FINHEAD(f1, v1, r1, 1)
        FINHEAD(f2, v2, r2, 2)
        FINHEAD(f3, v3, r3, 3)
        #undef FINHEAD
    }
}

// ---------------- launch ----------------
extern "C" void kernel_launch(void* const* d_in, const int* in_sizes, int n_in,
                              void* d_out, int out_size, void* d_ws, size_t ws_size,
                              hipStream_t stream) {
    const float* x     = (const float*)d_in[0];
    const void*  eidx  = d_in[1];
    const float* enc_W = (const float*)d_in[2];
    const float* enc_b = (const float*)d_in[3];
    const float* W1    = (const float*)d_in[4];
    const float* b1    = (const float*)d_in[5];
    const float* g1    = (const float*)d_in[6];
    const float* be1   = (const float*)d_in[7];
    const float* W2    = (const float*)d_in[8];
    const float* b2    = (const float*)d_in[9];
    const float* t     = (const float*)d_in[10];
    const float* ng    = (const float*)d_in[11];
    const float* nb    = (const float*)d_in[12];
    const float* linW  = (const float*)d_in[13];
    const float* linb  = (const float*)d_in[14];
    float* out = (float*)d_out;

    // workspace layout (~56 MB)
    float* A      = (float*)d_ws;                       // [N,64]
    float* B      = A + (size_t)GN_N * GN_H;            // [N,64]
    int*   rowptr = (int*)(B + (size_t)GN_N * GN_H);    // N+1 (+pad)
    int*   cursor = rowptr + (GN_N + 8);                // N   (+pad)
    int*   csr_src= cursor + (GN_N + 8);                // E
    int*   blksums= csr_src + GN_E;                     // <=128
    int*   flag   = blksums + 128;

    const int nblk = (GN_N + 1023) / 1024;              // 98

    // ---- CSR build (every call: ws is re-poisoned) ----
    k_prep   <<<(GN_N + 255) / 256, 256, 0, stream>>>(cursor, (const long long*)eidx, flag);
    k_hist   <<<(GN_E + 255) / 256, 256, 0, stream>>>(eidx, flag, cursor);
    k_scan1  <<<nblk, 1024, 0, stream>>>(cursor, rowptr, blksums);
    k_scan2  <<<1, 128, 0, stream>>>(blksums, nblk);
    k_scan3  <<<nblk, 1024, 0, stream>>>(rowptr, cursor, blksums);
    k_scatter<<<(GN_E + 255) / 256, 256, 0, stream>>>(eidx, flag, cursor, csr_src);

    // ---- encoder ----
    k_enc<<<GN_N / 32, 256, 0, stream>>>(x, enc_W, enc_b, A);

    // ---- conv 0 (pre-loop, mode 0): A -> B ----
    k_conv_agg<<<GN_N / 4, 256, 0, stream>>>(A, rowptr, csr_src, t, 0, B);
    k_conv_mlp<<<512, 256, 0, stream>>>(B, A, W1, b1, g1, be1, W2, b2,
                                        ng, nb, ng, nb, linW, linb, out, 0);

    // ---- DeepGCN res-blocks (last one fuses the final head, mode 2) ----
    float* cur = B; float* alt = A;
    for (int l = 0; l < 3; ++l) {
        k_conv_agg<<<GN_N / 4, 256, 0, stream>>>(cur, rowptr, csr_src, t, l, alt);
        k_conv_mlp<<<512, 256, 0, stream>>>(alt, cur,
            W1 + (size_t)l * GN_H * GN_2H, b1 + (size_t)l * GN_2H,
            g1 + (size_t)l * GN_2H,        be1 + (size_t)l * GN_2H,
            W2 + (size_t)l * GN_2H * GN_H, b2 + (size_t)l * GN_H,
            ng + (size_t)l * GN_H,         nb + (size_t)l * GN_H,
            ng, nb, linW, linb, out, (l == 2) ? 2 : 1);
        float* tmp = cur; cur = alt; alt = tmp;
    }
}

// Round 6
// 1166.407 us; speedup vs baseline: 1.2982x; 1.2982x over previous
//
#include <hip/hip_runtime.h>
#include <hip/hip_bf16.h>
#include <math.h>

// ---------------- problem constants ----------------
constexpr int GN_N  = 100000;   // nodes
constexpr int GN_E  = 1000000;  // edges
constexpr int GN_F  = 500;      // input features
constexpr int GN_H  = 64;       // hidden
constexpr int GN_2H = 128;      // mlp hidden
constexpr int GN_C  = 3;        // classes
constexpr float GN_EPS_MSG = 1e-7f;
constexpr float GN_LN_EPS  = 1e-5f;

// ---------------- prep: zero cursor + edge-dtype detect (parallel) ----------
// Reference declares int64 edge_index, but JAX without x64 delivers int32. An
// int64 view of random int32 index pairs has hi-word = another random index
// (nonzero w.h.p.), so 256 parallel 0<=v<N range checks <=> real int64.
__global__ void k_prep(int* __restrict__ cursor, const long long* __restrict__ e64,
                       int* __restrict__ flag) {
    int i = blockIdx.x * blockDim.x + threadIdx.x;
    if (i < GN_N) cursor[i] = 0;
    if (blockIdx.x == 0) {
        __shared__ int ok;
        if (threadIdx.x == 0) ok = 1;
        __syncthreads();
        long long v = e64[threadIdx.x];          // 256 parallel loads, 1 round trip
        if (v < 0 || v >= (long long)GN_N) ok = 0; // benign race: all write 0
        __syncthreads();
        if (threadIdx.x == 0) *flag = ok;
    }
}

// ---------------- CSR build ----------------
__global__ void k_hist(const void* eidx, const int* __restrict__ flag,
                       int* __restrict__ deg) {
    int e = blockIdx.x * blockDim.x + threadIdx.x;
    if (e >= GN_E) return;
    int d;
    if (*flag) d = (int)((const long long*)eidx)[GN_E + e];
    else       d = ((const int*)eidx)[GN_E + e];
    atomicAdd(&deg[d], 1);
}

__global__ void k_scan1(const int* __restrict__ deg, int* __restrict__ rowptr,
                        int* __restrict__ blksums) {
    __shared__ int sh[1024];
    int tid = threadIdx.x;
    int i = blockIdx.x * 1024 + tid;
    int v = (i < GN_N) ? deg[i] : 0;
    sh[tid] = v;
    __syncthreads();
    for (int o = 1; o < 1024; o <<= 1) {
        int add = (tid >= o) ? sh[tid - o] : 0;
        __syncthreads();
        sh[tid] += add;
        __syncthreads();
    }
    if (i < GN_N) rowptr[i + 1] = sh[tid];
    if (tid == 1023) blksums[blockIdx.x] = sh[1023];
}

// one-block parallel exclusive scan of the <=128 block sums
__global__ void k_scan2(int* __restrict__ blksums, int nblk) {
    __shared__ int sh[128];
    int tid = threadIdx.x;               // 128 threads
    int v = (tid < nblk) ? blksums[tid] : 0;
    sh[tid] = v;
    __syncthreads();
    for (int o = 1; o < 128; o <<= 1) {
        int add = (tid >= o) ? sh[tid - o] : 0;
        __syncthreads();
        sh[tid] += add;
        __syncthreads();
    }
    if (tid < nblk) blksums[tid] = sh[tid] - v;   // exclusive
}

// finalizes rowptr AND initializes the scatter cursor (fused)
__global__ void k_scan3(int* __restrict__ rowptr, int* __restrict__ cursor,
                        const int* __restrict__ blksums) {
    int i = blockIdx.x * 1024 + threadIdx.x;
    if (i < GN_N) {
        int v = rowptr[i + 1] + blksums[blockIdx.x];
        rowptr[i + 1] = v;
        cursor[i + 1] = v;   // cursor has +8 pad; [N] write is safe
    }
    if (i == 0) { rowptr[0] = 0; cursor[0] = 0; }
}

__global__ void k_scatter(const void* eidx, const int* __restrict__ flag,
                          int* __restrict__ cursor, int* __restrict__ csr_src) {
    int e = blockIdx.x * blockDim.x + threadIdx.x;
    if (e >= GN_E) return;
    int s, d;
    if (*flag) { const long long* p = (const long long*)eidx; s = (int)p[e]; d = (int)p[GN_E + e]; }
    else       { const int*       p = (const int*)eidx;       s = p[e];      d = p[GN_E + e]; }
    int pos = atomicAdd(&cursor[d], 1);
    csr_src[pos] = s;
}

// ---------------- encoder: h = x @ enc_W + enc_b ----------------
// Tiled GEMM. Block = 256 threads -> 64x64 output tile; K tiled by 100.
// x tile (64x100) and W tile (100x64) staged in LDS via lane-parallel
// coalesced float4 loads (fixes r4's latency-bound wave-uniform x loads:
// VALUBusy was 28%, HBM 3%). Thread (ty,tx) computes 4 rows x 4 cols.
// Per k: 4 LDS b32 (x, 2-way bcast conflict = free) + 1 b128 (w) + 16 FMA.
// LDS 51.2 KB -> 3 blocks/CU.
constexpr int ENC_BM = 64;
constexpr int ENC_KT = 100;
__global__ __launch_bounds__(256) void k_enc(const float* __restrict__ x,
        const float* __restrict__ W, const float* __restrict__ b,
        float* __restrict__ out) {
    __shared__ float xs[ENC_BM][ENC_KT];   // 25.6 KB
    __shared__ float ws[ENC_KT][GN_H];     // 25.6 KB
    int tid = threadIdx.x;
    int ty = tid >> 4;                      // 0..15 row group
    int tx = tid & 15;                      // 0..15 col group
    int row0 = blockIdx.x * ENC_BM;
    float4 acc0 = {0,0,0,0}, acc1 = {0,0,0,0}, acc2 = {0,0,0,0}, acc3 = {0,0,0,0};
    for (int kt = 0; kt < GN_F; kt += ENC_KT) {
        __syncthreads();                    // protect previous tile
        // x tile: 64 rows x 25 float4, coalesced (lanes walk columns of a row)
        #pragma unroll
        for (int idx = tid; idx < ENC_BM * (ENC_KT / 4); idx += 256) {
            int r  = idx / (ENC_KT / 4);
            int c4 = idx % (ENC_KT / 4);
            int gr = row0 + r; if (gr >= GN_N) gr = GN_N - 1;  // clamp (stores guarded)
            *(float4*)&xs[r][c4 * 4] =
                *(const float4*)&x[(size_t)gr * GN_F + kt + c4 * 4];
        }
        // w tile: 100 rows x 16 float4, coalesced
        #pragma unroll
        for (int idx = tid; idx < ENC_KT * (GN_H / 4); idx += 256) {
            int r  = idx / (GN_H / 4);
            int c4 = idx % (GN_H / 4);
            *(float4*)&ws[r][c4 * 4] =
                *(const float4*)&W[(size_t)(kt + r) * GN_H + c4 * 4];
        }
        __syncthreads();
        #pragma unroll 4
        for (int k = 0; k < ENC_KT; ++k) {
            float xv0 = xs[ty * 4 + 0][k];
            float xv1 = xs[ty * 4 + 1][k];
            float xv2 = xs[ty * 4 + 2][k];
            float xv3 = xs[ty * 4 + 3][k];
            float4 wv = *(const float4*)&ws[k][tx * 4];
            acc0.x += xv0 * wv.x; acc0.y += xv0 * wv.y; acc0.z += xv0 * wv.z; acc0.w += xv0 * wv.w;
            acc1.x += xv1 * wv.x; acc1.y += xv1 * wv.y; acc1.z += xv1 * wv.z; acc1.w += xv1 * wv.w;
            acc2.x += xv2 * wv.x; acc2.y += xv2 * wv.y; acc2.z += xv2 * wv.z; acc2.w += xv2 * wv.w;
            acc3.x += xv3 * wv.x; acc3.y += xv3 * wv.y; acc3.z += xv3 * wv.z; acc3.w += xv3 * wv.w;
        }
    }
    float4 bias = *(const float4*)&b[tx * 4];
    #define ENC_STORE(i, accv)                                                 \
    {   int gr = row0 + ty * 4 + i;                                            \
        if (gr < GN_N) {                                                       \
            float4 o; o.x = accv.x + bias.x; o.y = accv.y + bias.y;            \
            o.z = accv.z + bias.z; o.w = accv.w + bias.w;                      \
            *(float4*)&out[(size_t)gr * GN_H + tx * 4] = o;                    \
        } }
    ENC_STORE(0, acc0) ENC_STORE(1, acc1) ENC_STORE(2, acc2) ENC_STORE(3, acc3)
    #undef ENC_STORE
}

// ---------------- GENConv softmax aggregation (online, single pass) ----------
// One wave per dst node, lane = channel. Online softmax (re-association of the
// reference's max-then-sum; agg = num/den == sum(m * a/denom), denom uniform
// per dst). Edge loop unrolled x4: four independent 256B h[src] gathers in
// flight per dependent online-update chain segment.
__global__ __launch_bounds__(256) void k_conv_agg(const float* __restrict__ h,
        const int* __restrict__ rowptr, const int* __restrict__ csr_src,
        const float* __restrict__ t_all, int layer, float* __restrict__ out) {
    int lane = threadIdx.x & 63;
    int node = blockIdx.x * 4 + (threadIdx.x >> 6);
    if (node >= GN_N) return;
    float t = t_all[layer];
    int beg = rowptr[node], end = rowptr[node + 1];
    float mx = -INFINITY, den = 0.f, num = 0.f;
    #define AGG_EDGE(vv)                                                       \
    {   float m = fmaxf(vv, 0.f) + GN_EPS_MSG;                                 \
        float z = m * t;                                                       \
        float nm = fmaxf(mx, z);                                               \
        float sc = __expf(mx - nm);                                            \
        float a  = __expf(z - nm);                                             \
        den = den * sc + a;                                                    \
        num = num * sc + m * a;                                                \
        mx = nm; }
    int e = beg;
    for (; e + 3 < end; e += 4) {
        int s0 = csr_src[e];
        int s1 = csr_src[e + 1];
        int s2 = csr_src[e + 2];
        int s3 = csr_src[e + 3];
        float v0 = h[(size_t)s0 * GN_H + lane];   // 4 independent gathers
        float v1 = h[(size_t)s1 * GN_H + lane];   // all in flight before the
        float v2 = h[(size_t)s2 * GN_H + lane];   // dependent update chain
        float v3 = h[(size_t)s3 * GN_H + lane];
        AGG_EDGE(v0) AGG_EDGE(v1) AGG_EDGE(v2) AGG_EDGE(v3)
    }
    for (; e < end; ++e) {
        int s = csr_src[e];
        float v = h[(size_t)s * GN_H + lane];
        AGG_EDGE(v)
    }
    #undef AGG_EDGE
    float agg = (end > beg) ? (num / den) : 0.f;
    out[(size_t)node * GN_H + lane] = agg + h[(size_t)node * GN_H + lane];
}

// ---------------- GENConv MLP (+ DeepGCN post-block / + fused final head) ----
// One wave per FOUR nodes. W1/W2 in 64 KB LDS + 12 KB wave-private staging
// (76 KB -> 2 blocks/CU). Operand broadcast via uniform-address LDS reads.
// mode 0: buf[n] = mlp(buf[n])
// mode 1: buf[n] = h_old[n] + relu(LN(mlp(buf[n]), ng, nb))
// mode 2: mode 1, then out[n] = relu(LN(r, ng0, nb0)) @ linW + linb
//         (no buf write -- saves a 25.6MB store + the separate final kernel)
__global__ __launch_bounds__(256) void k_conv_mlp(float* buf,
        const float* __restrict__ h_old,
        const float* __restrict__ W1, const float* __restrict__ b1,
        const float* __restrict__ g1, const float* __restrict__ be1,
        const float* __restrict__ W2, const float* __restrict__ b2,
        const float* __restrict__ ng, const float* __restrict__ nb,
        const float* __restrict__ ng0, const float* __restrict__ nb0,
        const float* __restrict__ linW, const float* __restrict__ linb,
        float* __restrict__ out, int mode) {
    __shared__ float w1s[GN_H * GN_2H];     // 32 KB, [k][j] j=0..127
    __shared__ float w2s[GN_2H * GN_H];     // 32 KB, [j][c] c=0..63
    __shared__ float xbuf[4][4][GN_H];      //  4 KB, [wave][node][k]
    __shared__ float hbuf[4][4][GN_2H];     //  8 KB, [wave][node][j]
    int tid = threadIdx.x;
    for (int i = tid * 4; i < GN_H * GN_2H; i += 256 * 4) {
        *(float4*)&w1s[i] = *(const float4*)&W1[i];
        *(float4*)&w2s[i] = *(const float4*)&W2[i];
    }
    __syncthreads();
    int lane = tid & 63;
    int wid  = tid >> 6;
    float b1a = b1[2 * lane], b1b = b1[2 * lane + 1];
    float g1a = g1[2 * lane], g1b = g1[2 * lane + 1];
    float e1a = be1[2 * lane], e1b = be1[2 * lane + 1];
    float b2c = b2[lane];
    float ngc = ng[lane], nbc = nb[lane];
    float ng0c = ng0[lane], nb0c = nb0[lane];
    float lw0 = linW[lane * GN_C + 0];
    float lw1 = linW[lane * GN_C + 1];
    float lw2 = linW[lane * GN_C + 2];

    for (int n0 = blockIdx.x * 16 + wid * 4; n0 < GN_N; n0 += gridDim.x * 16) {
        // stage the 4 input vectors (lane k of node n) into wave-private LDS
        xbuf[wid][0][lane] = buf[(size_t)(n0 + 0) * GN_H + lane];
        xbuf[wid][1][lane] = buf[(size_t)(n0 + 1) * GN_H + lane];
        xbuf[wid][2][lane] = buf[(size_t)(n0 + 2) * GN_H + lane];
        xbuf[wid][3][lane] = buf[(size_t)(n0 + 3) * GN_H + lane];
        // ---- y1[j] = dot(in, W1[:,j]) + b1[j]; lane holds j=2*lane, 2*lane+1
        float a00 = b1a, a01 = b1b, a10 = b1a, a11 = b1b;
        float a20 = b1a, a21 = b1b, a30 = b1a, a31 = b1b;
        #pragma unroll
        for (int k = 0; k < GN_H; k += 4) {
            float4 x0 = *(const float4*)&xbuf[wid][0][k];   // uniform-addr
            float4 x1 = *(const float4*)&xbuf[wid][1][k];   // broadcast reads
            float4 x2 = *(const float4*)&xbuf[wid][2][k];
            float4 x3 = *(const float4*)&xbuf[wid][3][k];
            #pragma unroll
            for (int kk = 0; kk < 4; ++kk) {
                float2 w = *(const float2*)&w1s[(k + kk) * GN_2H + 2 * lane];
                float e0 = (&x0.x)[kk], e1 = (&x1.x)[kk];
                float e2 = (&x2.x)[kk], e3 = (&x3.x)[kk];
                a00 += e0 * w.x; a01 += e0 * w.y;
                a10 += e1 * w.x; a11 += e1 * w.y;
                a20 += e2 * w.x; a21 += e2 * w.y;
                a30 += e3 * w.x; a31 += e3 * w.y;
            }
        }
        // ---- LayerNorm over 128 + relu, per node
        float s0 = a00 + a01, q0 = a00 * a00 + a01 * a01;
        float s1 = a10 + a11, q1 = a10 * a10 + a11 * a11;
        float s2 = a20 + a21, q2 = a20 * a20 + a21 * a21;
        float s3 = a30 + a31, q3 = a30 * a30 + a31 * a31;
        #pragma unroll
        for (int o = 1; o < 64; o <<= 1) {
            s0 += __shfl_xor(s0, o); q0 += __shfl_xor(q0, o);
            s1 += __shfl_xor(s1, o); q1 += __shfl_xor(q1, o);
            s2 += __shfl_xor(s2, o); q2 += __shfl_xor(q2, o);
            s3 += __shfl_xor(s3, o); q3 += __shfl_xor(q3, o);
        }
        #define LN128(sv, qv, aA, aB, hA, hB)                                  \
        float hA, hB;                                                          \
        {   float mu = sv * (1.f / 128.f);                                     \
            float var = qv * (1.f / 128.f) - mu * mu;                          \
            float rstd = rsqrtf(var + GN_LN_EPS);                              \
            hA = fmaxf((aA - mu) * rstd * g1a + e1a, 0.f);                     \
            hB = fmaxf((aB - mu) * rstd * g1b + e1b, 0.f); }
        LN128(s0, q0, a00, a01, h00, h01)
        LN128(s1, q1, a10, a11, h10, h11)
        LN128(s2, q2, a20, a21, h20, h21)
        LN128(s3, q3, a30, a31, h30, h31)
        #undef LN128
        // stage h1 (lane holds j=2l,2l+1 -> contiguous b64 write per node)
        *(float2*)&hbuf[wid][0][2 * lane] = make_float2(h00, h01);
        *(float2*)&hbuf[wid][1][2 * lane] = make_float2(h10, h11);
        *(float2*)&hbuf[wid][2][2 * lane] = make_float2(h20, h21);
        *(float2*)&hbuf[wid][3][2 * lane] = make_float2(h30, h31);
        // ---- y2[c] = dot(h1, W2[:,c]) + b2[c]; lane = c
        float c0 = b2c, c1 = b2c, c2 = b2c, c3 = b2c;
        #pragma unroll
        for (int j = 0; j < GN_2H; j += 4) {
            float w0 = w2s[(j + 0) * GN_H + lane];
            float w1 = w2s[(j + 1) * GN_H + lane];
            float w2 = w2s[(j + 2) * GN_H + lane];
            float w3 = w2s[(j + 3) * GN_H + lane];
            float4 hv0 = *(const float4*)&hbuf[wid][0][j];  // uniform-addr
            float4 hv1 = *(const float4*)&hbuf[wid][1][j];  // broadcast reads
            float4 hv2 = *(const float4*)&hbuf[wid][2][j];
            float4 hv3 = *(const float4*)&hbuf[wid][3][j];
            c0 += hv0.x * w0 + hv0.y * w1 + hv0.z * w2 + hv0.w * w3;
            c1 += hv1.x * w0 + hv1.y * w1 + hv1.z * w2 + hv1.w * w3;
            c2 += hv2.x * w0 + hv2.y * w1 + hv2.z * w2 + hv2.w * w3;
            c3 += hv3.x * w0 + hv3.y * w1 + hv3.z * w2 + hv3.w * w3;
        }
        if (mode == 0) {
            buf[(size_t)(n0 + 0) * GN_H + lane] = c0;
            buf[(size_t)(n0 + 1) * GN_H + lane] = c1;
            buf[(size_t)(n0 + 2) * GN_H + lane] = c2;
            buf[(size_t)(n0 + 3) * GN_H + lane] = c3;
            continue;
        }
        // ---- DeepGCN post-block: r = h_old + relu(LN64(c, ng, nb))
        float t0 = c0, u0 = c0 * c0, t1 = c1, u1 = c1 * c1;
        float t2 = c2, u2 = c2 * c2, t3 = c3, u3 = c3 * c3;
        #pragma unroll
        for (int o = 1; o < 64; o <<= 1) {
            t0 += __shfl_xor(t0, o); u0 += __shfl_xor(u0, o);
            t1 += __shfl_xor(t1, o); u1 += __shfl_xor(u1, o);
            t2 += __shfl_xor(t2, o); u2 += __shfl_xor(u2, o);
            t3 += __shfl_xor(t3, o); u3 += __shfl_xor(u3, o);
        }
        float r0, r1, r2, r3;
        #define LN64(tv, uv, cv, rv, idx)                                      \
        {   float mu = tv * (1.f / 64.f);                                      \
            float var = uv * (1.f / 64.f) - mu * mu;                           \
            float rstd = rsqrtf(var + GN_LN_EPS);                              \
            float cvn = fmaxf((cv - mu) * rstd * ngc + nbc, 0.f);              \
            rv = h_old[(size_t)(n0 + idx) * GN_H + lane] + cvn; }
        LN64(t0, u0, c0, r0, 0)
        LN64(t1, u1, c1, r1, 1)
        LN64(t2, u2, c2, r2, 2)
        LN64(t3, u3, c3, r3, 3)
        #undef LN64
        if (mode == 1) {
            buf[(size_t)(n0 + 0) * GN_H + lane] = r0;
            buf[(size_t)(n0 + 1) * GN_H + lane] = r1;
            buf[(size_t)(n0 + 2) * GN_H + lane] = r2;
            buf[(size_t)(n0 + 3) * GN_H + lane] = r3;
            continue;
        }
        // ---- mode 2: fused final head, out[n] = relu(LN64(r, ng0, nb0)) @ linW + linb
        float f0 = r0, v0 = r0 * r0, f1 = r1, v1 = r1 * r1;
        float f2 = r2, v2 = r2 * r2, f3 = r3, v3 = r3 * r3;
        #pragma unroll
        for (int o = 1; o < 64; o <<= 1) {
            f0 += __shfl_xor(f0, o); v0 += __shfl_xor(v0, o);
            f1 += __shfl_xor(f1, o); v1 += __shfl_xor(v1, o);
            f2 += __shfl_xor(f2, o); v2 += __shfl_xor(v2, o);
            f3 += __shfl_xor(f3, o); v3 += __shfl_xor(v3, o);
        }
        #define FINHEAD(fv, vv, rv, idx)                                       \
        {   float mu = fv * (1.f / 64.f);                                      \
            float var = vv * (1.f / 64.f) - mu * mu;                           \
            float rstd = rsqrtf(var + GN_LN_EPS);                              \
            float hn = fmaxf((rv - mu) * rstd * ng0c + nb0c, 0.f);             \
            float p0 = hn * lw0, p1 = hn * lw1, p2 = hn * lw2;                 \
            _Pragma("unroll")                                                  \
            for (int o = 1; o < 64; o <<= 1) {                                 \
                p0 += __shfl_xor(p0, o);                                       \
                p1 += __shfl_xor(p1, o);                                       \
                p2 += __shfl_xor(p2, o);                                       \
            }                                                                  \
            if (lane == 0) {                                                   \
                out[(size_t)(n0 + idx) * GN_C + 0] = p0 + linb[0];             \
                out[(size_t)(n0 + idx) * GN_C + 1] = p1 + linb[1];             \
                out[(size_t)(n0 + idx) * GN_C + 2] = p2 + linb[2];             \
            } }
        FINHEAD(f0, v0, r0, 0)
        FINHEAD(f1, v1, r1, 1)
        FINHEAD(f2, v2, r2, 2)
        FINHEAD(f3, v3, r3, 3)
        #undef FINHEAD
    }
}

// ---------------- launch ----------------
extern "C" void kernel_launch(void* const* d_in, const int* in_sizes, int n_in,
                              void* d_out, int out_size, void* d_ws, size_t ws_size,
                              hipStream_t stream) {
    const float* x     = (const float*)d_in[0];
    const void*  eidx  = d_in[1];
    const float* enc_W = (const float*)d_in[2];
    const float* enc_b = (const float*)d_in[3];
    const float* W1    = (const float*)d_in[4];
    const float* b1    = (const float*)d_in[5];
    const float* g1    = (const float*)d_in[6];
    const float* be1   = (const float*)d_in[7];
    const float* W2    = (const float*)d_in[8];
    const float* b2    = (const float*)d_in[9];
    const float* t     = (const float*)d_in[10];
    const float* ng    = (const float*)d_in[11];
    const float* nb    = (const float*)d_in[12];
    const float* linW  = (const float*)d_in[13];
    const float* linb  = (const float*)d_in[14];
    float* out = (float*)d_out;

    // workspace layout (~56 MB)
    float* A      = (float*)d_ws;                       // [N,64]
    float* B      = A + (size_t)GN_N * GN_H;            // [N,64]
    int*   rowptr = (int*)(B + (size_t)GN_N * GN_H);    // N+1 (+pad)
    int*   cursor = rowptr + (GN_N + 8);                // N   (+pad)
    int*   csr_src= cursor + (GN_N + 8);                // E
    int*   blksums= csr_src + GN_E;                     // <=128
    int*   flag   = blksums + 128;

    const int nblk = (GN_N + 1023) / 1024;              // 98

    // ---- CSR build (every call: ws is re-poisoned) ----
    k_prep   <<<(GN_N + 255) / 256, 256, 0, stream>>>(cursor, (const long long*)eidx, flag);
    k_hist   <<<(GN_E + 255) / 256, 256, 0, stream>>>(eidx, flag, cursor);
    k_scan1  <<<nblk, 1024, 0, stream>>>(cursor, rowptr, blksums);
    k_scan2  <<<1, 128, 0, stream>>>(blksums, nblk);
    k_scan3  <<<nblk, 1024, 0, stream>>>(rowptr, cursor, blksums);
    k_scatter<<<(GN_E + 255) / 256, 256, 0, stream>>>(eidx, flag, cursor, csr_src);

    // ---- encoder (tiled GEMM, 64-row blocks) ----
    k_enc<<<(GN_N + ENC_BM - 1) / ENC_BM, 256, 0, stream>>>(x, enc_W, enc_b, A);

    // ---- conv 0 (pre-loop, mode 0): A -> B ----
    k_conv_agg<<<GN_N / 4, 256, 0, stream>>>(A, rowptr, csr_src, t, 0, B);
    k_conv_mlp<<<512, 256, 0, stream>>>(B, A, W1, b1, g1, be1, W2, b2,
                                        ng, nb, ng, nb, linW, linb, out, 0);

    // ---- DeepGCN res-blocks (last one fuses the final head, mode 2) ----
    float* cur = B; float* alt = A;
    for (int l = 0; l < 3; ++l) {
        k_conv_agg<<<GN_N / 4, 256, 0, stream>>>(cur, rowptr, csr_src, t, l, alt);
        k_conv_mlp<<<512, 256, 0, stream>>>(alt, cur,
            W1 + (size_t)l * GN_H * GN_2H, b1 + (size_t)l * GN_2H,
            g1 + (size_t)l * GN_2H,        be1 + (size_t)l * GN_2H,
            W2 + (size_t)l * GN_2H * GN_H, b2 + (size_t)l * GN_H,
            ng + (size_t)l * GN_H,         nb + (size_t)l * GN_H,
            ng, nb, linW, linb, out, (l == 2) ? 2 : 1);
        float* tmp = cur; cur = alt; alt = tmp;
    }
}

// Round 7
// 1132.081 us; speedup vs baseline: 1.3375x; 1.0303x over previous
//
#include <hip/hip_runtime.h>
#include <hip/hip_bf16.h>
#include <math.h>

// ---------------- problem constants ----------------
constexpr int GN_N  = 100000;   // nodes
constexpr int GN_E  = 1000000;  // edges
constexpr int GN_F  = 500;      // input features
constexpr int GN_H  = 64;       // hidden
constexpr int GN_2H = 128;      // mlp hidden
constexpr int GN_C  = 3;        // classes
constexpr float GN_EPS_MSG = 1e-7f;
constexpr float GN_LN_EPS  = 1e-5f;

// ---------------- prep: zero cursor + edge-dtype detect (parallel) ----------
__global__ void k_prep(int* __restrict__ cursor, const long long* __restrict__ e64,
                       int* __restrict__ flag) {
    int i = blockIdx.x * blockDim.x + threadIdx.x;
    if (i < GN_N) cursor[i] = 0;
    if (blockIdx.x == 0) {
        __shared__ int ok;
        if (threadIdx.x == 0) ok = 1;
        __syncthreads();
        long long v = e64[threadIdx.x];
        if (v < 0 || v >= (long long)GN_N) ok = 0;
        __syncthreads();
        if (threadIdx.x == 0) *flag = ok;
    }
}

// ---------------- CSR build ----------------
__global__ void k_hist(const void* eidx, const int* __restrict__ flag,
                       int* __restrict__ deg) {
    int e = blockIdx.x * blockDim.x + threadIdx.x;
    if (e >= GN_E) return;
    int d;
    if (*flag) d = (int)((const long long*)eidx)[GN_E + e];
    else       d = ((const int*)eidx)[GN_E + e];
    atomicAdd(&deg[d], 1);
}

__global__ void k_scan1(const int* __restrict__ deg, int* __restrict__ rowptr,
                        int* __restrict__ blksums) {
    __shared__ int sh[1024];
    int tid = threadIdx.x;
    int i = blockIdx.x * 1024 + tid;
    int v = (i < GN_N) ? deg[i] : 0;
    sh[tid] = v;
    __syncthreads();
    for (int o = 1; o < 1024; o <<= 1) {
        int add = (tid >= o) ? sh[tid - o] : 0;
        __syncthreads();
        sh[tid] += add;
        __syncthreads();
    }
    if (i < GN_N) rowptr[i + 1] = sh[tid];
    if (tid == 1023) blksums[blockIdx.x] = sh[1023];
}

__global__ void k_scan2(int* __restrict__ blksums, int nblk) {
    __shared__ int sh[128];
    int tid = threadIdx.x;
    int v = (tid < nblk) ? blksums[tid] : 0;
    sh[tid] = v;
    __syncthreads();
    for (int o = 1; o < 128; o <<= 1) {
        int add = (tid >= o) ? sh[tid - o] : 0;
        __syncthreads();
        sh[tid] += add;
        __syncthreads();
    }
    if (tid < nblk) blksums[tid] = sh[tid] - v;   // exclusive
}

__global__ void k_scan3(int* __restrict__ rowptr, int* __restrict__ cursor,
                        const int* __restrict__ blksums) {
    int i = blockIdx.x * 1024 + threadIdx.x;
    if (i < GN_N) {
        int v = rowptr[i + 1] + blksums[blockIdx.x];
        rowptr[i + 1] = v;
        cursor[i + 1] = v;
    }
    if (i == 0) { rowptr[0] = 0; cursor[0] = 0; }
}

__global__ void k_scatter(const void* eidx, const int* __restrict__ flag,
                          int* __restrict__ cursor, int* __restrict__ csr_src) {
    int e = blockIdx.x * blockDim.x + threadIdx.x;
    if (e >= GN_E) return;
    int s, d;
    if (*flag) { const long long* p = (const long long*)eidx; s = (int)p[e]; d = (int)p[GN_E + e]; }
    else       { const int*       p = (const int*)eidx;       s = p[e];      d = p[GN_E + e]; }
    int pos = atomicAdd(&cursor[d], 1);
    csr_src[pos] = s;
}

// ---------------- encoder: h = x @ enc_W + enc_b ----------------
// r6 post-mortem: the 4xb32+1xb128 per wave-k inner loop = ~35 cyc on the
// CU-SHARED LDS pipe -> 178us model == 184us measured. Fix the instr ratio:
// 8x8 register tile per thread, k-major LDS so each operand read is one
// broadcast b128 covering 4 rows/cols (8 distinct addrs -> 2-way alias, free).
// Per wave-k: 4 b128 (~24-48 cyc LDS) vs 64 FMA (128 cyc VALU, per-SIMD).
// Staging transposes conflict-free: thread owns one x row, float2 loads
// (L1-resident lines), 2x b32 writes at bank tid%32.
constexpr int ENC_BM = 128;
constexpr int ENC_KT = 50;                  // 500 = 10 * 50
__global__ __launch_bounds__(128) void k_enc(const float* __restrict__ x,
        const float* __restrict__ W, const float* __restrict__ b,
        float* __restrict__ out) {
    __shared__ float xs[ENC_KT][ENC_BM];    // k-major, 25.6 KB
    __shared__ float ws[ENC_KT][GN_H];      // k-major, 12.8 KB
    int tid = threadIdx.x;                  // 128 threads = 2 waves
    int ty = tid >> 3;                      // 0..15: rows ty*8..+7
    int tx = tid & 7;                       // 0..7 : cols tx*8..+7
    int row0 = blockIdx.x * ENC_BM;
    float acc[8][8];
    #pragma unroll
    for (int i = 0; i < 8; ++i)
        #pragma unroll
        for (int j = 0; j < 8; ++j) acc[i][j] = 0.f;

    int grow = row0 + tid; if (grow >= GN_N) grow = GN_N - 1;   // clamp reads
    const float* xrow = x + (size_t)grow * GN_F;

    for (int kt = 0; kt < GN_F; kt += ENC_KT) {
        __syncthreads();                    // protect previous tile
        // stage x transposed: thread stages its OWN row (float2: 8B-aligned
        // for every kt; sequential chunks stay in L1). Writes bank = tid%32.
        #pragma unroll
        for (int i = 0; i < ENC_KT / 2; ++i) {
            float2 v = *(const float2*)&xrow[kt + 2 * i];
            xs[2 * i][tid]     = v.x;
            xs[2 * i + 1][tid] = v.y;
        }
        // stage ws (natural k-major, coalesced float4)
        for (int idx = tid; idx < ENC_KT * (GN_H / 4); idx += 128) {
            int r = idx >> 4, c4 = idx & 15;
            *(float4*)&ws[r][c4 * 4] =
                *(const float4*)&W[(size_t)(kt + r) * GN_H + c4 * 4];
        }
        __syncthreads();
        #pragma unroll 2
        for (int k = 0; k < ENC_KT; ++k) {
            float4 xa = *(const float4*)&xs[k][ty * 8];
            float4 xb = *(const float4*)&xs[k][ty * 8 + 4];
            float4 wa = *(const float4*)&ws[k][tx * 8];
            float4 wb = *(const float4*)&ws[k][tx * 8 + 4];
            float xr[8] = {xa.x, xa.y, xa.z, xa.w, xb.x, xb.y, xb.z, xb.w};
            float wc[8] = {wa.x, wa.y, wa.z, wa.w, wb.x, wb.y, wb.z, wb.w};
            #pragma unroll
            for (int i = 0; i < 8; ++i)
                #pragma unroll
                for (int j = 0; j < 8; ++j)
                    acc[i][j] += xr[i] * wc[j];
        }
    }
    float4 ba = *(const float4*)&b[tx * 8];
    float4 bb = *(const float4*)&b[tx * 8 + 4];
    #pragma unroll
    for (int i = 0; i < 8; ++i) {
        int gr = row0 + ty * 8 + i;
        if (gr < GN_N) {
            float4 o0, o1;
            o0.x = acc[i][0] + ba.x; o0.y = acc[i][1] + ba.y;
            o0.z = acc[i][2] + ba.z; o0.w = acc[i][3] + ba.w;
            o1.x = acc[i][4] + bb.x; o1.y = acc[i][5] + bb.y;
            o1.z = acc[i][6] + bb.z; o1.w = acc[i][7] + bb.w;
            *(float4*)&out[(size_t)gr * GN_H + tx * 8]     = o0;
            *(float4*)&out[(size_t)gr * GN_H + tx * 8 + 4] = o1;
        }
    }
}

// ---------------- GENConv softmax aggregation (online, single pass) ----------
__global__ __launch_bounds__(256) void k_conv_agg(const float* __restrict__ h,
        const int* __restrict__ rowptr, const int* __restrict__ csr_src,
        const float* __restrict__ t_all, int layer, float* __restrict__ out) {
    int lane = threadIdx.x & 63;
    int node = blockIdx.x * 4 + (threadIdx.x >> 6);
    if (node >= GN_N) return;
    float t = t_all[layer];
    int beg = rowptr[node], end = rowptr[node + 1];
    float mx = -INFINITY, den = 0.f, num = 0.f;
    #define AGG_EDGE(vv)                                                       \
    {   float m = fmaxf(vv, 0.f) + GN_EPS_MSG;                                 \
        float z = m * t;                                                       \
        float nm = fmaxf(mx, z);                                               \
        float sc = __expf(mx - nm);                                            \
        float a  = __expf(z - nm);                                             \
        den = den * sc + a;                                                    \
        num = num * sc + m * a;                                                \
        mx = nm; }
    int e = beg;
    for (; e + 3 < end; e += 4) {
        int s0 = csr_src[e];
        int s1 = csr_src[e + 1];
        int s2 = csr_src[e + 2];
        int s3 = csr_src[e + 3];
        float v0 = h[(size_t)s0 * GN_H + lane];
        float v1 = h[(size_t)s1 * GN_H + lane];
        float v2 = h[(size_t)s2 * GN_H + lane];
        float v3 = h[(size_t)s3 * GN_H + lane];
        AGG_EDGE(v0) AGG_EDGE(v1) AGG_EDGE(v2) AGG_EDGE(v3)
    }
    for (; e < end; ++e) {
        int s = csr_src[e];
        float v = h[(size_t)s * GN_H + lane];
        AGG_EDGE(v)
    }
    #undef AGG_EDGE
    float agg = (end > beg) ? (num / den) : 0.f;
    out[(size_t)node * GN_H + lane] = agg + h[(size_t)node * GN_H + lane];
}

// ---------------- GENConv MLP (+ DeepGCN post-block / + fused final head) ----
// W2 now staged TRANSPOSED with +132 row pad: lane c reads w2sT[c][j..j+3] as
// one per-lane b128 (12-cyc optimum) instead of 4x b32 (~23 cyc) per j-quad.
__global__ __launch_bounds__(256) void k_conv_mlp(float* buf,
        const float* __restrict__ h_old,
        const float* __restrict__ W1, const float* __restrict__ b1,
        const float* __restrict__ g1, const float* __restrict__ be1,
        const float* __restrict__ W2, const float* __restrict__ b2,
        const float* __restrict__ ng, const float* __restrict__ nb,
        const float* __restrict__ ng0, const float* __restrict__ nb0,
        const float* __restrict__ linW, const float* __restrict__ linb,
        float* __restrict__ out, int mode) {
    __shared__ float w1s[GN_H * GN_2H];     // 32 KB, [k][j]
    __shared__ float w2sT[GN_H][132];       // 33.8 KB, [c][j] (+pad 4)
    __shared__ float xbuf[4][4][GN_H];      //  4 KB
    __shared__ float hbuf[4][4][GN_2H];     //  8 KB
    int tid = threadIdx.x;
    for (int i = tid * 4; i < GN_H * GN_2H; i += 256 * 4)
        *(float4*)&w1s[i] = *(const float4*)&W1[i];
    for (int idx = tid; idx < GN_2H * (GN_H / 4); idx += 256) {
        int j = idx >> 4, c4 = idx & 15;
        float4 v = *(const float4*)&W2[(size_t)j * GN_H + c4 * 4];
        w2sT[c4 * 4 + 0][j] = v.x;
        w2sT[c4 * 4 + 1][j] = v.y;
        w2sT[c4 * 4 + 2][j] = v.z;
        w2sT[c4 * 4 + 3][j] = v.w;
    }
    __syncthreads();
    int lane = tid & 63;
    int wid  = tid >> 6;
    float b1a = b1[2 * lane], b1b = b1[2 * lane + 1];
    float g1a = g1[2 * lane], g1b = g1[2 * lane + 1];
    float e1a = be1[2 * lane], e1b = be1[2 * lane + 1];
    float b2c = b2[lane];
    float ngc = ng[lane], nbc = nb[lane];
    float ng0c = ng0[lane], nb0c = nb0[lane];
    float lw0 = linW[lane * GN_C + 0];
    float lw1 = linW[lane * GN_C + 1];
    float lw2 = linW[lane * GN_C + 2];

    for (int n0 = blockIdx.x * 16 + wid * 4; n0 < GN_N; n0 += gridDim.x * 16) {
        xbuf[wid][0][lane] = buf[(size_t)(n0 + 0) * GN_H + lane];
        xbuf[wid][1][lane] = buf[(size_t)(n0 + 1) * GN_H + lane];
        xbuf[wid][2][lane] = buf[(size_t)(n0 + 2) * GN_H + lane];
        xbuf[wid][3][lane] = buf[(size_t)(n0 + 3) * GN_H + lane];
        // ---- y1[j] = dot(in, W1[:,j]) + b1[j]; lane holds j=2*lane, 2*lane+1
        float a00 = b1a, a01 = b1b, a10 = b1a, a11 = b1b;
        float a20 = b1a, a21 = b1b, a30 = b1a, a31 = b1b;
        #pragma unroll
        for (int k = 0; k < GN_H; k += 4) {
            float4 x0 = *(const float4*)&xbuf[wid][0][k];
            float4 x1 = *(const float4*)&xbuf[wid][1][k];
            float4 x2 = *(const float4*)&xbuf[wid][2][k];
            float4 x3 = *(const float4*)&xbuf[wid][3][k];
            #pragma unroll
            for (int kk = 0; kk < 4; ++kk) {
                float2 w = *(const float2*)&w1s[(k + kk) * GN_2H + 2 * lane];
                float e0 = (&x0.x)[kk], e1 = (&x1.x)[kk];
                float e2 = (&x2.x)[kk], e3 = (&x3.x)[kk];
                a00 += e0 * w.x; a01 += e0 * w.y;
                a10 += e1 * w.x; a11 += e1 * w.y;
                a20 += e2 * w.x; a21 += e2 * w.y;
                a30 += e3 * w.x; a31 += e3 * w.y;
            }
        }
        // ---- LayerNorm over 128 + relu
        float s0 = a00 + a01, q0 = a00 * a00 + a01 * a01;
        float s1 = a10 + a11, q1 = a10 * a10 + a11 * a11;
        float s2 = a20 + a21, q2 = a20 * a20 + a21 * a21;
        float s3 = a30 + a31, q3 = a30 * a30 + a31 * a31;
        #pragma unroll
        for (int o = 1; o < 64; o <<= 1) {
            s0 += __shfl_xor(s0, o); q0 += __shfl_xor(q0, o);
            s1 += __shfl_xor(s1, o); q1 += __shfl_xor(q1, o);
            s2 += __shfl_xor(s2, o); q2 += __shfl_xor(q2, o);
            s3 += __shfl_xor(s3, o); q3 += __shfl_xor(q3, o);
        }
        #define LN128(sv, qv, aA, aB, hA, hB)                                  \
        float hA, hB;                                                          \
        {   float mu = sv * (1.f / 128.f);                                     \
            float var = qv * (1.f / 128.f) - mu * mu;                          \
            float rstd = rsqrtf(var + GN_LN_EPS);                              \
            hA = fmaxf((aA - mu) * rstd * g1a + e1a, 0.f);                     \
            hB = fmaxf((aB - mu) * rstd * g1b + e1b, 0.f); }
        LN128(s0, q0, a00, a01, h00, h01)
        LN128(s1, q1, a10, a11, h10, h11)
        LN128(s2, q2, a20, a21, h20, h21)
        LN128(s3, q3, a30, a31, h30, h31)
        #undef LN128
        *(float2*)&hbuf[wid][0][2 * lane] = make_float2(h00, h01);
        *(float2*)&hbuf[wid][1][2 * lane] = make_float2(h10, h11);
        *(float2*)&hbuf[wid][2][2 * lane] = make_float2(h20, h21);
        *(float2*)&hbuf[wid][3][2 * lane] = make_float2(h30, h31);
        // ---- y2[c] = dot(h1, W2[:,c]) + b2[c]; lane = c, b128 weight reads
        float c0 = b2c, c1 = b2c, c2 = b2c, c3 = b2c;
        #pragma unroll
        for (int j4 = 0; j4 < GN_2H; j4 += 4) {
            float4 w  = *(const float4*)&w2sT[lane][j4];
            float4 hv0 = *(const float4*)&hbuf[wid][0][j4];
            float4 hv1 = *(const float4*)&hbuf[wid][1][j4];
            float4 hv2 = *(const float4*)&hbuf[wid][2][j4];
            float4 hv3 = *(const float4*)&hbuf[wid][3][j4];
            c0 += hv0.x * w.x + hv0.y * w.y + hv0.z * w.z + hv0.w * w.w;
            c1 += hv1.x * w.x + hv1.y * w.y + hv1.z * w.z + hv1.w * w.w;
            c2 += hv2.x * w.x + hv2.y * w.y + hv2.z * w.z + hv2.w * w.w;
            c3 += hv3.x * w.x + hv3.y * w.y + hv3.z * w.z + hv3.w * w.w;
        }
        if (mode == 0) {
            buf[(size_t)(n0 + 0) * GN_H + lane] = c0;
            buf[(size_t)(n0 + 1) * GN_H + lane] = c1;
            buf[(size_t)(n0 + 2) * GN_H + lane] = c2;
            buf[(size_t)(n0 + 3) * GN_H + lane] = c3;
            continue;
        }
        // ---- DeepGCN post-block: r = h_old + relu(LN64(c, ng, nb))
        float t0 = c0, u0 = c0 * c0, t1 = c1, u1 = c1 * c1;
        float t2 = c2, u2 = c2 * c2, t3 = c3, u3 = c3 * c3;
        #pragma unroll
        for (int o = 1; o < 64; o <<= 1) {
            t0 += __shfl_xor(t0, o); u0 += __shfl_xor(u0, o);
            t1 += __shfl_xor(t1, o); u1 += __shfl_xor(u1, o);
            t2 += __shfl_xor(t2, o); u2 += __shfl_xor(u2, o);
            t3 += __shfl_xor(t3, o); u3 += __shfl_xor(u3, o);
        }
        float r0, r1, r2, r3;
        #define LN64(tv, uv, cv, rv, idx)                                      \
        {   float mu = tv * (1.f / 64.f);                                      \
            float var = uv * (1.f / 64.f) - mu * mu;                           \
            float rstd = rsqrtf(var + GN_LN_EPS);                              \
            float cvn = fmaxf((cv - mu) * rstd * ngc + nbc, 0.f);              \
            rv = h_old[(size_t)(n0 + idx) * GN_H + lane] + cvn; }
        LN64(t0, u0, c0, r0, 0)
        LN64(t1, u1, c1, r1, 1)
        LN64(t2, u2, c2, r2, 2)
        LN64(t3, u3, c3, r3, 3)
        #undef LN64
        if (mode == 1) {
            buf[(size_t)(n0 + 0) * GN_H + lane] = r0;
            buf[(size_t)(n0 + 1) * GN_H + lane] = r1;
            buf[(size_t)(n0 + 2) * GN_H + lane] = r2;
            buf[(size_t)(n0 + 3) * GN_H + lane] = r3;
            continue;
        }
        // ---- mode 2: fused final head
        float f0 = r0, v0 = r0 * r0, f1 = r1, v1 = r1 * r1;
        float f2 = r2, v2 = r2 * r2, f3 = r3, v3 = r3 * r3;
        #pragma unroll
        for (int o = 1; o < 64; o <<= 1) {
            f0 += __shfl_xor(f0, o); v0 += __shfl_xor(v0, o);
            f1 += __shfl_xor(f1, o); v1 += __shfl_xor(v1, o);
            f2 += __shfl_xor(f2, o); v2 += __shfl_xor(v2, o);
            f3 += __shfl_xor(f3, o); v3 += __shfl_xor(v3, o);
        }
        #define FINHEAD(fv, vv, rv, idx)                                       \
        {   float mu = fv * (1.f / 64.f);                                      \
            float var = vv * (1.f / 64.f) - mu * mu;                           \
            float rstd = rsqrtf(var + GN_LN_EPS);                              \
            float hn = fmaxf((rv - mu) * rstd * ng0c + nb0c, 0.f);             \
            float p0 = hn * lw0, p1 = hn * lw1, p2 = hn * lw2;                 \
            _Pragma("unroll")                                                  \
            for (int o = 1; o < 64; o <<= 1) {                                 \
                p0 += __shfl_xor(p0, o);                                       \
                p1 += __shfl_xor(p1, o);                                       \
                p2 += __shfl_xor(p2, o);                                       \
            }                                                                  \
            if (lane == 0) {                                                   \
                out[(size_t)(n0 + idx) * GN_C + 0] = p0 + linb[0];             \
                out[(size_t)(n0 + idx) * GN_C + 1] = p1 + linb[1];             \
                out[(size_t)(n0 + idx) * GN_C + 2] = p2 + linb[2];             \
            } }
        FINHEAD(f0, v0, r0, 0)
        FINHEAD(f1, v1, r1, 1)
        FINHEAD(f2, v2, r2, 2)
        FINHEAD(f3, v3, r3, 3)
        #undef FINHEAD
    }
}

// ---------------- launch ----------------
extern "C" void kernel_launch(void* const* d_in, const int* in_sizes, int n_in,
                              void* d_out, int out_size, void* d_ws, size_t ws_size,
                              hipStream_t stream) {
    const float* x     = (const float*)d_in[0];
    const void*  eidx  = d_in[1];
    const float* enc_W = (const float*)d_in[2];
    const float* enc_b = (const float*)d_in[3];
    const float* W1    = (const float*)d_in[4];
    const float* b1    = (const float*)d_in[5];
    const float* g1    = (const float*)d_in[6];
    const float* be1   = (const float*)d_in[7];
    const float* W2    = (const float*)d_in[8];
    const float* b2    = (const float*)d_in[9];
    const float* t     = (const float*)d_in[10];
    const float* ng    = (const float*)d_in[11];
    const float* nb    = (const float*)d_in[12];
    const float* linW  = (const float*)d_in[13];
    const float* linb  = (const float*)d_in[14];
    float* out = (float*)d_out;

    float* A      = (float*)d_ws;                       // [N,64]
    float* B      = A + (size_t)GN_N * GN_H;            // [N,64]
    int*   rowptr = (int*)(B + (size_t)GN_N * GN_H);    // N+1 (+pad)
    int*   cursor = rowptr + (GN_N + 8);                // N   (+pad)
    int*   csr_src= cursor + (GN_N + 8);                // E
    int*   blksums= csr_src + GN_E;                     // <=128
    int*   flag   = blksums + 128;

    const int nblk = (GN_N + 1023) / 1024;              // 98

    // ---- CSR build ----
    k_prep   <<<(GN_N + 255) / 256, 256, 0, stream>>>(cursor, (const long long*)eidx, flag);
    k_hist   <<<(GN_E + 255) / 256, 256, 0, stream>>>(eidx, flag, cursor);
    k_scan1  <<<nblk, 1024, 0, stream>>>(cursor, rowptr, blksums);
    k_scan2  <<<1, 128, 0, stream>>>(blksums, nblk);
    k_scan3  <<<nblk, 1024, 0, stream>>>(rowptr, cursor, blksums);
    k_scatter<<<(GN_E + 255) / 256, 256, 0, stream>>>(eidx, flag, cursor, csr_src);

    // ---- encoder (8x8 register-tiled, k-major LDS, 128-thread blocks) ----
    k_enc<<<(GN_N + ENC_BM - 1) / ENC_BM, 128, 0, stream>>>(x, enc_W, enc_b, A);

    // ---- conv 0 (pre-loop, mode 0): A -> B ----
    k_conv_agg<<<GN_N / 4, 256, 0, stream>>>(A, rowptr, csr_src, t, 0, B);
    k_conv_mlp<<<512, 256, 0, stream>>>(B, A, W1, b1, g1, be1, W2, b2,
                                        ng, nb, ng, nb, linW, linb, out, 0);

    // ---- DeepGCN res-blocks (last fuses the final head, mode 2) ----
    float* cur = B; float* alt = A;
    for (int l = 0; l < 3; ++l) {
        k_conv_agg<<<GN_N / 4, 256, 0, stream>>>(cur, rowptr, csr_src, t, l, alt);
        k_conv_mlp<<<512, 256, 0, stream>>>(alt, cur,
            W1 + (size_t)l * GN_H * GN_2H, b1 + (size_t)l * GN_2H,
            g1 + (size_t)l * GN_2H,        be1 + (size_t)l * GN_2H,
            W2 + (size_t)l * GN_2H * GN_H, b2 + (size_t)l * GN_H,
            ng + (size_t)l * GN_H,         nb + (size_t)l * GN_H,
            ng, nb, linW, linb, out, (l == 2) ? 2 : 1);
        float* tmp = cur; cur = alt; alt = tmp;
    }
}